// Round 7
// baseline (562.042 us; speedup 1.0000x reference)
//
#include <hip/hip_runtime.h>
#include <hip/hip_bf16.h>

// ---------------- problem constants ----------------
constexpr int B = 64;
constexpr int NG = 16;
constexpr int NSH = 112;
constexpr int N = 128;          // nodes per graph
constexpr int NN = B * N;       // 8192 total nodes
constexpr int L = 5;

// ---------------- workspace layout (float offsets) ----------------
constexpr int OFF_H     = 0;                    // [8192][32] f32
constexpr int OFF_P     = OFF_H + NN * 32;      // [8192][2]  f32
constexpr int OFF_TEMB0 = OFF_P + NN * 2;       // [64][32]
constexpr int OFF_TEMB1 = OFF_TEMB0 + B * 32;
constexpr int OFF_HA    = OFF_TEMB1 + B * 32;   // [8192][32] f32 (h[dst]-term + temb-term + b_msg1)
constexpr int OFF_HB    = OFF_HA + NN * 32;     // [8192][32] stored as ushort bf16 (h[src]-term)
constexpr int OFF_AGH   = OFF_HB + NN * 32;     // [8192][32] f32
constexpr int OFF_AGP   = OFF_AGH + NN * 32;    // [8192][2]  f32

typedef __attribute__((ext_vector_type(8))) short bf16x8;
typedef __attribute__((ext_vector_type(4))) float f32x4;

// ---------------- math helpers ----------------
__device__ __forceinline__ float fsigmoid(float x) {
    return __builtin_amdgcn_rcpf(1.0f + __expf(-x));
}
__device__ __forceinline__ float fsilu(float x) { return x * fsigmoid(x); }
__device__ __forceinline__ short f2bfs(float f) {           // RNE (setup paths only)
    union { __hip_bfloat16 b; short s; } u; u.b = __float2bfloat16(f); return u.s;
}
__device__ __forceinline__ float bf2f(unsigned short u) {
    union { unsigned int i; float f; } v; v.i = ((unsigned int)u) << 16; return v.f;
}
// single-inst truncation pack: dst = bf16(hi)<<16 | bf16(lo)
__device__ __forceinline__ unsigned int pk_trunc(float lo, float hi) {
    union { float f; unsigned int u; } a, b;
    a.f = hi; b.f = lo;
    return __builtin_amdgcn_perm(a.u, b.u, 0x07060302u);
}

// ---------------- setup: init h / p / temb0 ----------------
__global__ __launch_bounds__(256) void setup_kernel(
    const float* __restrict__ pos, const int* __restrict__ timesteps,
    const float* __restrict__ goal_pos,
    const float* __restrict__ W_hin, const float* __restrict__ b_hin,
    float* __restrict__ ws)
{
    int idx = blockIdx.x * 256 + threadIdx.x;

    if (idx < NN * 32) {                       // h init: goals use W_hin row 0, shelves row 1
        int c = idx & 31; int node = idx >> 5; int local = node & 127;
        int row = (local < NG) ? 0 : 1;
        ws[OFF_H + idx] = W_hin[row * 32 + c] + b_hin[c];
        return;
    }
    idx -= NN * 32;
    if (idx < NN * 2) {                        // p init
        int d = idx & 1; int node = idx >> 1; int g = node >> 7; int local = node & 127;
        float v = (local < NG) ? goal_pos[local * 2 + d]
                               : pos[(g * NSH + (local - NG)) * 2 + d];
        ws[OFF_P + idx] = v;
        return;
    }
    idx -= NN * 2;
    if (idx < B * 32) {                        // sinusoidal timestep embedding
        int j = idx & 31; int g = idx >> 5;
        float t = (float)timesteps[g];
        int jj = (j < 16) ? j : (j - 16);
        float freq = expf(-logf(10000.0f) * (float)jj / 16.0f);
        float ang = t * freq;
        ws[OFF_TEMB0 + idx] = (j < 16) ? cosf(ang) : sinf(ang);
    }
}

// ---------------- layer-0 node precompute: HA (f32), HBh (bf16) ----------------
__global__ __launch_bounds__(256) void pre_kernel(
    float* __restrict__ R,
    const float* __restrict__ W_msg1, const float* __restrict__ b_msg1,
    const float* __restrict__ tembIn, int layer)
{
    int tid = blockIdx.x * 256 + threadIdx.x;   // 0 .. 262143
    int c = tid & 31; int node = tid >> 5; int g = node >> 7;
    const float* __restrict__ W1 = W_msg1 + layer * 97 * 32;
    float accA = b_msg1[layer * 32 + c];
    float accB = 0.f;
#pragma unroll
    for (int k = 0; k < 32; ++k) {
        float hk = R[OFF_H + node * 32 + k];
        accA += hk * W1[k * 32 + c];
        accB += hk * W1[(32 + k) * 32 + c];
    }
#pragma unroll
    for (int k = 0; k < 32; ++k)
        accA += tembIn[g * 32 + k] * W1[(65 + k) * 32 + c];
    R[OFF_HA + tid] = accA;
    ((unsigned short*)(R + OFF_HB))[tid] = (unsigned short)f2bfs(accB);
}

// ---------------- edge kernel (MFMA): messages + gated aggregation ----------------
// grid: 64 graphs x 32 dst-groups = 2048 blocks, 256 thr = 4 waves.
// Per-tile fused pipeline (phase1->2->3 per 16-row tile): accumulator liveness
// 8 regs/tile instead of 32, mbuf 5 KB instead of 20 KB. waves_per_eu(5):
// <=102-VGPR budget -> 5 waves/SIMD (was VGPR-limited at 4).
__global__ __attribute__((amdgpu_flat_work_group_size(256, 256)))
__attribute__((amdgpu_waves_per_eu(5))) void edge_kernel(
    float* __restrict__ R,
    const float* __restrict__ W_msg1,
    const float* __restrict__ W_msg2, const float* __restrict__ b_msg2,
    const float* __restrict__ W_att, const float* __restrict__ b_att,
    const float* __restrict__ W_pos1, const float* __restrict__ b_pos1,
    const float* __restrict__ W_pos2, const float* __restrict__ b_pos2,
    float* __restrict__ aggh, float* __restrict__ aggp, int layer)
{
    __shared__ unsigned short sHBh[128 * 40];   // bf16, row stride 40 (80B, 16B-aligned)
    __shared__ float sPx[128], sPy[128];
    __shared__ unsigned int mbuf[4 * 16 * 20];  // per-wave 16-row tile staging (reused per tt)
    __shared__ float2 spn[4][64];               // per-wave (pnx,pny) row-broadcast buffer

    const int t = threadIdx.x;
    const int bx = blockIdx.x;
    const int g = bx >> 5;
    const int gbase = g * 128;

    // ---- stage HBh (graph's 128x32 bf16) + positions ----
    const unsigned short* HBH = (const unsigned short*)(R + OFF_HB);
#pragma unroll
    for (int ch = 0; ch < 2; ++ch) {
        int chunk = t + ch * 256;               // 512 chunks of 8 bf16
        int row = chunk >> 2, g4 = chunk & 3;
        uint4 v = *(const uint4*)(HBH + (gbase + row) * 32 + (g4 << 3));
        *(uint4*)(sHBh + row * 40 + (g4 << 3)) = v;
    }
    if (t < 128) {
        sPx[t] = R[OFF_P + (gbase + t) * 2];
        sPy[t] = R[OFF_P + (gbase + t) * 2 + 1];
    }
    __syncthreads();

    const int lane = t & 63, w = t >> 6;
    const int c = lane & 15;
    const int rg = lane >> 4;
    const int kk = rg << 3;
    const int dloc = ((bx & 31) << 2) | w;
    const int dstNode = gbase + dloc;

    // ---- resident weight fragments (bf16, RNE one-time) ----
    const float* __restrict__ Wm2L = W_msg2 + layer * 1024;
    const float* __restrict__ Wp1L = W_pos1 + layer * 1024;
    bf16x8 WB1c0, WB1c1, WBpc0, WBpc1, WBac;
#pragma unroll
    for (int j = 0; j < 8; ++j) {
        WB1c0[j] = f2bfs(Wm2L[(kk + j) * 32 + c]);
        WB1c1[j] = f2bfs(Wm2L[(kk + j) * 32 + c + 16]);
        int pk = ((kk + j) & 1) * 16 + ((kk + j) >> 1);   // pi-permuted k for staged A
        WBpc0[j] = f2bfs(Wp1L[pk * 32 + c]);
        WBpc1[j] = f2bfs(Wp1L[pk * 32 + c + 16]);
        WBac[j]  = f2bfs(W_att[layer * 32 + pk]);         // column-replicated
    }

    // ---- per-dst / per-lane constants ----
    float vha[8], vwr[8];
    {
        const float* haR = R + OFF_HA + dstNode * 32 + kk;
        const float* wrR = W_msg1 + layer * 97 * 32 + 64 * 32 + kk;
#pragma unroll
        for (int j = 0; j < 8; ++j) { vha[j] = haR[j]; vwr[j] = wrR[j]; }
    }
    const float batt   = b_att[layer];
    const float vbm20  = b_msg2[layer * 32 + c], vbm21 = b_msg2[layer * 32 + c + 16];
    const float vbp10  = b_pos1[layer * 32 + c], vbp11 = b_pos1[layer * 32 + c + 16];
    const float vwp20  = W_pos2[layer * 32 + c], vwp21 = W_pos2[layer * 32 + c + 16];
    const float bp2    = b_pos2[layer];
    const float pxd = R[OFF_P + dstNode * 2], pyd = R[OFF_P + dstNode * 2 + 1];

    unsigned int* mb = mbuf + w * 16 * 20;

    float aghc0 = 0.f, aghc1 = 0.f, apx = 0.f, apy = 0.f, spnx = 0.f, spny = 0.f;

#pragma unroll 1
    for (int half = 0; half < 2; ++half) {
        // ---- per-src geometry (lane = src within half) ----
        const int src = (half << 6) + lane;
        const float dx = pxd - sPx[src];
        const float dy = pyd - sPy[src];
        const float radial = dx * dx + dy * dy;
        const float inv = __builtin_amdgcn_rcpf(__builtin_amdgcn_sqrtf(radial) + 1e-6f);
        const float pnx = dx * inv, pny = dy * inv;
        spnx += pnx; spny += pny;
        spn[w][lane] = (float2){pnx, pny};

        // ---- fused per-tile pipeline: 16 edge rows at a time ----
#pragma unroll
        for (int tt = 0; tt < 4; ++tt) {
            // phase 1: build m1 A-frag (trunc pack), GEMM-1
            const float rad_t = __shfl(radial, c + (tt << 4));
            uint4 hraw = *(const uint4*)(sHBh + ((half << 6) + c + (tt << 4)) * 40 + kk);
            const unsigned short* hs = (const unsigned short*)&hraw;
            float x[8];
#pragma unroll
            for (int j = 0; j < 8; ++j)
                x[j] = fsilu(vha[j] + bf2f(hs[j]) + rad_t * vwr[j]);
            union { unsigned int u[4]; bf16x8 v; } af;
#pragma unroll
            for (int d = 0; d < 4; ++d) af.u[d] = pk_trunc(x[2 * d], x[2 * d + 1]);
            f32x4 a0 = (f32x4){vbm20, vbm20, vbm20, vbm20};
            f32x4 a1 = (f32x4){vbm21, vbm21, vbm21, vbm21};
            a0 = __builtin_amdgcn_mfma_f32_16x16x32_bf16(af.v, WB1c0, a0, 0, 0, 0);
            a1 = __builtin_amdgcn_mfma_f32_16x16x32_bf16(af.v, WB1c1, a1, 0, 0, 0);

            // phase 2: silu, stage UNGATED s tile (pi-packed bf16 pairs, trunc)
            float s0[4], s1[4];
#pragma unroll
            for (int j = 0; j < 4; ++j) {
                s0[j] = fsilu(a0[j]);
                s1[j] = fsilu(a1[j]);
                mb[((rg << 2) + j) * 20 + c] = pk_trunc(s0[j], s1[j]);
            }

            // phase 3: attz MFMA + z MFMAs from staged tile, gate/pw/aggregate
            union { uint4 u; bf16x8 v; } qa;
            qa.u = *(const uint4*)(mb + c * 20 + (rg << 2));
            f32x4 za = (f32x4){batt, batt, batt, batt};
            f32x4 z0 = (f32x4){0.f, 0.f, 0.f, 0.f};
            f32x4 z1 = (f32x4){0.f, 0.f, 0.f, 0.f};
            za = __builtin_amdgcn_mfma_f32_16x16x32_bf16(qa.v, WBac,  za, 0, 0, 0);
            z0 = __builtin_amdgcn_mfma_f32_16x16x32_bf16(qa.v, WBpc0, z0, 0, 0, 0);
            z1 = __builtin_amdgcn_mfma_f32_16x16x32_bf16(qa.v, WBpc1, z1, 0, 0, 0);
#pragma unroll
            for (int j = 0; j < 4; ++j) {
                const float att = fsigmoid(za[j]);
                aghc0 += att * s0[j];
                aghc1 += att * s1[j];
                const float q0 = fsilu(att * z0[j] + vbp10);
                const float q1 = fsilu(att * z1[j] + vbp11);
                const float pwp = q0 * vwp20 + q1 * vwp21;
                const float2 pn = spn[w][(tt << 4) + (rg << 2) + j];
                apx += pwp * pn.x;
                apy += pwp * pn.y;
            }
        }
    }

    // ---- epilogue: reductions + stores ----
    aghc0 += __shfl_xor(aghc0, 16); aghc0 += __shfl_xor(aghc0, 32);
    aghc1 += __shfl_xor(aghc1, 16); aghc1 += __shfl_xor(aghc1, 32);
#pragma unroll
    for (int off = 1; off < 64; off <<= 1) {
        apx  += __shfl_xor(apx, off);
        apy  += __shfl_xor(apy, off);
        spnx += __shfl_xor(spnx, off);
        spny += __shfl_xor(spny, off);
    }
    if (lane < 16)       aggh[dstNode * 32 + lane] = aghc0;
    else if (lane < 32)  aggh[dstNode * 32 + lane] = aghc1;
    if (lane == 0) {
        aggp[dstNode * 2]     = (apx + bp2 * spnx) * (1.0f / 128.0f);
        aggp[dstNode * 2 + 1] = (apy + bp2 * spny) * (1.0f / 128.0f);
    }
}

// ---------------- fused node update + pre(layer+1) ----------------
// thread = (node, channel); 1024 blocks x 256 thr; block = 8 nodes (one graph).
// temb update recomputed per block (trivial); one writer block per graph.
__global__ __launch_bounds__(256) void node_kernel(
    float* __restrict__ ws,
    const float* __restrict__ W_node1, const float* __restrict__ b_node1,
    const float* __restrict__ W_node2, const float* __restrict__ b_node2,
    const float* __restrict__ W_t, const float* __restrict__ b_t,
    const float* __restrict__ W_msg1, const float* __restrict__ b_msg1,
    int layer)
{
    __shared__ float sIn[8][64];    // h (0..31) | aggh (32..63) per local node
    __shared__ float sU1[8][32];
    __shared__ float sHn[8][32];
    __shared__ float sTold[32], sTnew[32];

    const int tid = blockIdx.x * 256 + threadIdx.x;   // (node, c)
    const int c = tid & 31;
    const int node = tid >> 5;
    const int ln = (threadIdx.x >> 5) & 7;
    const int g = node >> 7;

    const float* __restrict__ Wn1 = W_node1 + layer * 2048;
    const float* __restrict__ Wn2 = W_node2 + layer * 1024;

    sIn[ln][c]      = ws[OFF_H + node * 32 + c];
    sIn[ln][32 + c] = ws[OFF_AGH + node * 32 + c];
    if (threadIdx.x < 32)
        sTold[threadIdx.x] = ws[((layer & 1) ? OFF_TEMB1 : OFF_TEMB0) + g * 32 + threadIdx.x];
    __syncthreads();

    float acc = b_node1[layer * 32 + c];
#pragma unroll
    for (int k = 0; k < 32; ++k)
        acc += sIn[ln][k] * Wn1[k * 32 + c] + sIn[ln][32 + k] * Wn1[(32 + k) * 32 + c];
    sU1[ln][c] = fsilu(acc);
    if (threadIdx.x < 32) {                          // temb update (per-block recompute)
        const float* Wt = W_t + layer * 1024;
        float a2 = b_t[layer * 32 + threadIdx.x];
#pragma unroll
        for (int k = 0; k < 32; ++k) a2 += sTold[k] * Wt[k * 32 + threadIdx.x];
        sTnew[threadIdx.x] = fsilu(a2);
    }
    __syncthreads();

    float u = b_node2[layer * 32 + c];
#pragma unroll
    for (int k = 0; k < 32; ++k) u += sU1[ln][k] * Wn2[k * 32 + c];
    const float hn = (u > 0.f ? u : 0.01f * u) + sIn[ln][c];
    ws[OFF_H + node * 32 + c] = hn;
    sHn[ln][c] = hn;

    if (c < 2)                                       // p += aggr_p (2 lanes per node)
        ws[OFF_P + node * 2 + c] += ws[OFF_AGP + node * 2 + c];
    if ((blockIdx.x & 15) == 0 && threadIdx.x < 32)  // persist new temb (1 block/graph)
        ws[((layer & 1) ? OFF_TEMB0 : OFF_TEMB1) + g * 32 + threadIdx.x] = sTnew[threadIdx.x];
    __syncthreads();

    // fused pre for layer+1: HA (f32) + HBh (bf16) from hn, sTnew
    const float* __restrict__ W1 = W_msg1 + (layer + 1) * 97 * 32;
    float accA = b_msg1[(layer + 1) * 32 + c];
    float accB = 0.f;
#pragma unroll
    for (int k = 0; k < 32; ++k) {
        const float hk = sHn[ln][k];
        accA += hk * W1[k * 32 + c];
        accB += hk * W1[(32 + k) * 32 + c];
    }
#pragma unroll
    for (int k = 0; k < 32; ++k)
        accA += sTnew[k] * W1[(65 + k) * 32 + c];
    ws[OFF_HA + node * 32 + c] = accA;
    ((unsigned short*)(ws + OFF_HB))[node * 32 + c] = (unsigned short)f2bfs(accB);
}

// ---------------- final: p += aggr_p for shelves, emit fp32 ----------------
__global__ __launch_bounds__(256) void out_kernel(const float* __restrict__ R,
                                                  float* __restrict__ out)
{
    const int o = blockIdx.x * 256 + threadIdx.x;     // 0..14335
    if (o >= B * NSH * 2) return;
    const int d = o & 1;
    const int s = (o >> 1) % NSH;
    const int b = (o >> 1) / NSH;
    const int node = b * 128 + NG + s;
    out[o] = R[OFF_P + node * 2 + d] + R[OFF_AGP + node * 2 + d];
}

// ---------------- launch ----------------
extern "C" void kernel_launch(void* const* d_in, const int* in_sizes, int n_in,
                              void* d_out, int out_size, void* d_ws, size_t ws_size,
                              hipStream_t stream)
{
    const float* pos      = (const float*)d_in[0];
    const int*   tsteps   = (const int*)d_in[1];
    const float* goal_pos = (const float*)d_in[2];
    const float* W_hin    = (const float*)d_in[3];
    const float* b_hin    = (const float*)d_in[4];
    const float* W_msg1   = (const float*)d_in[5];
    const float* b_msg1   = (const float*)d_in[6];
    const float* W_msg2   = (const float*)d_in[7];
    const float* b_msg2   = (const float*)d_in[8];
    const float* W_att    = (const float*)d_in[9];
    const float* b_att    = (const float*)d_in[10];
    const float* W_pos1   = (const float*)d_in[11];
    const float* b_pos1   = (const float*)d_in[12];
    const float* W_pos2   = (const float*)d_in[13];
    const float* b_pos2   = (const float*)d_in[14];
    const float* W_node1  = (const float*)d_in[15];
    const float* b_node1  = (const float*)d_in[16];
    const float* W_node2  = (const float*)d_in[17];
    const float* b_node2  = (const float*)d_in[18];
    const float* W_t      = (const float*)d_in[19];
    const float* b_t      = (const float*)d_in[20];

    float* ws = (float*)d_ws;

    constexpr int setup_threads = NN * 32 + NN * 2 + B * 32;
    setup_kernel<<<(setup_threads + 255) / 256, 256, 0, stream>>>(
        pos, tsteps, goal_pos, W_hin, b_hin, ws);
    pre_kernel<<<NN * 32 / 256, 256, 0, stream>>>(ws, W_msg1, b_msg1, ws + OFF_TEMB0, 0);

    for (int l = 0; l < L; ++l) {
        edge_kernel<<<2048, 256, 0, stream>>>(ws, W_msg1, W_msg2, b_msg2, W_att, b_att,
                                              W_pos1, b_pos1, W_pos2, b_pos2,
                                              ws + OFF_AGH, ws + OFF_AGP, l);
        if (l < L - 1)
            node_kernel<<<NN * 32 / 256, 256, 0, stream>>>(ws, W_node1, b_node1, W_node2,
                                                           b_node2, W_t, b_t, W_msg1, b_msg1, l);
    }
    out_kernel<<<(B * NSH * 2 + 255) / 256, 256, 0, stream>>>(ws, (float*)d_out);
}

// Round 8
// 308.318 us; speedup vs baseline: 1.8229x; 1.8229x over previous
//
#include <hip/hip_runtime.h>
#include <hip/hip_bf16.h>

// ---------------- problem constants ----------------
constexpr int B = 64;
constexpr int NG = 16;
constexpr int NSH = 112;
constexpr int N = 128;          // nodes per graph
constexpr int NN = B * N;       // 8192 total nodes
constexpr int L = 5;

// ---------------- workspace layout (float offsets) ----------------
constexpr int OFF_H     = 0;                    // [8192][32] f32
constexpr int OFF_P     = OFF_H + NN * 32;      // [8192][2]  f32
constexpr int OFF_TEMB0 = OFF_P + NN * 2;       // [64][32]
constexpr int OFF_TEMB1 = OFF_TEMB0 + B * 32;
constexpr int OFF_HA    = OFF_TEMB1 + B * 32;   // [8192][32] f32 (h[dst]-term + temb-term + b_msg1)
constexpr int OFF_HB    = OFF_HA + NN * 32;     // [8192][32] stored as ushort bf16 (h[src]-term)
constexpr int OFF_AGH   = OFF_HB + NN * 32;     // [8192][32] f32
constexpr int OFF_AGP   = OFF_AGH + NN * 32;    // [8192][2]  f32

typedef __attribute__((ext_vector_type(8))) short bf16x8;
typedef __attribute__((ext_vector_type(4))) float f32x4;

// ---------------- math helpers ----------------
__device__ __forceinline__ float fsigmoid(float x) {
    return __builtin_amdgcn_rcpf(1.0f + __expf(-x));
}
__device__ __forceinline__ float fsilu(float x) { return x * fsigmoid(x); }
__device__ __forceinline__ short f2bfs(float f) {           // RNE (setup paths only)
    union { __hip_bfloat16 b; short s; } u; u.b = __float2bfloat16(f); return u.s;
}
__device__ __forceinline__ float bf2f(unsigned short u) {
    union { unsigned int i; float f; } v; v.i = ((unsigned int)u) << 16; return v.f;
}
// single-inst truncation pack: dst = bf16(hi)<<16 | bf16(lo)
__device__ __forceinline__ unsigned int pk_trunc(float lo, float hi) {
    union { float f; unsigned int u; } a, b;
    a.f = hi; b.f = lo;
    return __builtin_amdgcn_perm(a.u, b.u, 0x07060302u);
}

// ---------------- setup: init h / p / temb0 ----------------
__global__ __launch_bounds__(256) void setup_kernel(
    const float* __restrict__ pos, const int* __restrict__ timesteps,
    const float* __restrict__ goal_pos,
    const float* __restrict__ W_hin, const float* __restrict__ b_hin,
    float* __restrict__ ws)
{
    int idx = blockIdx.x * 256 + threadIdx.x;

    if (idx < NN * 32) {                       // h init: goals use W_hin row 0, shelves row 1
        int c = idx & 31; int node = idx >> 5; int local = node & 127;
        int row = (local < NG) ? 0 : 1;
        ws[OFF_H + idx] = W_hin[row * 32 + c] + b_hin[c];
        return;
    }
    idx -= NN * 32;
    if (idx < NN * 2) {                        // p init
        int d = idx & 1; int node = idx >> 1; int g = node >> 7; int local = node & 127;
        float v = (local < NG) ? goal_pos[local * 2 + d]
                               : pos[(g * NSH + (local - NG)) * 2 + d];
        ws[OFF_P + idx] = v;
        return;
    }
    idx -= NN * 2;
    if (idx < B * 32) {                        // sinusoidal timestep embedding
        int j = idx & 31; int g = idx >> 5;
        float t = (float)timesteps[g];
        int jj = (j < 16) ? j : (j - 16);
        float freq = expf(-logf(10000.0f) * (float)jj / 16.0f);
        float ang = t * freq;
        ws[OFF_TEMB0 + idx] = (j < 16) ? cosf(ang) : sinf(ang);
    }
}

// ---------------- layer-0 node precompute: HA (f32), HBh (bf16) ----------------
__global__ __launch_bounds__(256) void pre_kernel(
    float* __restrict__ R,
    const float* __restrict__ W_msg1, const float* __restrict__ b_msg1,
    const float* __restrict__ tembIn, int layer)
{
    int tid = blockIdx.x * 256 + threadIdx.x;   // 0 .. 262143
    int c = tid & 31; int node = tid >> 5; int g = node >> 7;
    const float* __restrict__ W1 = W_msg1 + layer * 97 * 32;
    float accA = b_msg1[layer * 32 + c];
    float accB = 0.f;
#pragma unroll
    for (int k = 0; k < 32; ++k) {
        float hk = R[OFF_H + node * 32 + k];
        accA += hk * W1[k * 32 + c];
        accB += hk * W1[(32 + k) * 32 + c];
    }
#pragma unroll
    for (int k = 0; k < 32; ++k)
        accA += tembIn[g * 32 + k] * W1[(65 + k) * 32 + c];
    R[OFF_HA + tid] = accA;
    ((unsigned short*)(R + OFF_HB))[tid] = (unsigned short)f2bfs(accB);
}

// ---------------- edge kernel (MFMA): messages + gated aggregation ----------------
// grid: 64 graphs x 32 dst-groups = 2048 blocks, 256 thr = 4 waves.
// Per-tile fused pipeline. waves_per_eu(2,4): R6-proven config — >=128-VGPR
// budget, NO SPILLS. (waves_per_eu(5) forced 102-VGPR -> 216 MB scratch, 2.3x
// slower. 4 waves spill-free beats 5 waves spilling.)
__global__ __attribute__((amdgpu_flat_work_group_size(256, 256)))
__attribute__((amdgpu_waves_per_eu(2, 4))) void edge_kernel(
    float* __restrict__ R,
    const float* __restrict__ W_msg1,
    const float* __restrict__ W_msg2, const float* __restrict__ b_msg2,
    const float* __restrict__ W_att, const float* __restrict__ b_att,
    const float* __restrict__ W_pos1, const float* __restrict__ b_pos1,
    const float* __restrict__ W_pos2, const float* __restrict__ b_pos2,
    float* __restrict__ aggh, float* __restrict__ aggp, int layer)
{
    __shared__ unsigned short sHBh[128 * 40];   // bf16, row stride 40 (80B, 16B-aligned)
    __shared__ float sPx[128], sPy[128];
    __shared__ unsigned int mbuf[4 * 16 * 20];  // per-wave 16-row tile staging (reused per tt)
    __shared__ float2 spn[4][64];               // per-wave (pnx,pny) row-broadcast buffer

    const int t = threadIdx.x;
    const int bx = blockIdx.x;
    const int g = bx >> 5;
    const int gbase = g * 128;

    // ---- stage HBh (graph's 128x32 bf16) + positions ----
    const unsigned short* HBH = (const unsigned short*)(R + OFF_HB);
#pragma unroll
    for (int ch = 0; ch < 2; ++ch) {
        int chunk = t + ch * 256;               // 512 chunks of 8 bf16
        int row = chunk >> 2, g4 = chunk & 3;
        uint4 v = *(const uint4*)(HBH + (gbase + row) * 32 + (g4 << 3));
        *(uint4*)(sHBh + row * 40 + (g4 << 3)) = v;
    }
    if (t < 128) {
        sPx[t] = R[OFF_P + (gbase + t) * 2];
        sPy[t] = R[OFF_P + (gbase + t) * 2 + 1];
    }
    __syncthreads();

    const int lane = t & 63, w = t >> 6;
    const int c = lane & 15;
    const int rg = lane >> 4;
    const int kk = rg << 3;
    const int dloc = ((bx & 31) << 2) | w;
    const int dstNode = gbase + dloc;

    // ---- resident weight fragments (bf16, RNE one-time) ----
    const float* __restrict__ Wm2L = W_msg2 + layer * 1024;
    const float* __restrict__ Wp1L = W_pos1 + layer * 1024;
    bf16x8 WB1c0, WB1c1, WBpc0, WBpc1, WBac;
#pragma unroll
    for (int j = 0; j < 8; ++j) {
        WB1c0[j] = f2bfs(Wm2L[(kk + j) * 32 + c]);
        WB1c1[j] = f2bfs(Wm2L[(kk + j) * 32 + c + 16]);
        int pk = ((kk + j) & 1) * 16 + ((kk + j) >> 1);   // pi-permuted k for staged A
        WBpc0[j] = f2bfs(Wp1L[pk * 32 + c]);
        WBpc1[j] = f2bfs(Wp1L[pk * 32 + c + 16]);
        WBac[j]  = f2bfs(W_att[layer * 32 + pk]);         // column-replicated
    }

    // ---- per-dst / per-lane constants ----
    float vha[8], vwr[8];
    {
        const float* haR = R + OFF_HA + dstNode * 32 + kk;
        const float* wrR = W_msg1 + layer * 97 * 32 + 64 * 32 + kk;
#pragma unroll
        for (int j = 0; j < 8; ++j) { vha[j] = haR[j]; vwr[j] = wrR[j]; }
    }
    const float batt   = b_att[layer];
    const float vbm20  = b_msg2[layer * 32 + c], vbm21 = b_msg2[layer * 32 + c + 16];
    const float vbp10  = b_pos1[layer * 32 + c], vbp11 = b_pos1[layer * 32 + c + 16];
    const float vwp20  = W_pos2[layer * 32 + c], vwp21 = W_pos2[layer * 32 + c + 16];
    const float bp2    = b_pos2[layer];
    const float pxd = R[OFF_P + dstNode * 2], pyd = R[OFF_P + dstNode * 2 + 1];

    unsigned int* mb = mbuf + w * 16 * 20;

    float aghc0 = 0.f, aghc1 = 0.f, apx = 0.f, apy = 0.f, spnx = 0.f, spny = 0.f;

#pragma unroll 1
    for (int half = 0; half < 2; ++half) {
        // ---- per-src geometry (lane = src within half) ----
        const int src = (half << 6) + lane;
        const float dx = pxd - sPx[src];
        const float dy = pyd - sPy[src];
        const float radial = dx * dx + dy * dy;
        const float inv = __builtin_amdgcn_rcpf(__builtin_amdgcn_sqrtf(radial) + 1e-6f);
        const float pnx = dx * inv, pny = dy * inv;
        spnx += pnx; spny += pny;
        spn[w][lane] = (float2){pnx, pny};

        // ---- fused per-tile pipeline: 16 edge rows at a time ----
#pragma unroll
        for (int tt = 0; tt < 4; ++tt) {
            // phase 1: build m1 A-frag (trunc pack), GEMM-1
            const float rad_t = __shfl(radial, c + (tt << 4));
            uint4 hraw = *(const uint4*)(sHBh + ((half << 6) + c + (tt << 4)) * 40 + kk);
            const unsigned short* hs = (const unsigned short*)&hraw;
            float x[8];
#pragma unroll
            for (int j = 0; j < 8; ++j)
                x[j] = fsilu(vha[j] + bf2f(hs[j]) + rad_t * vwr[j]);
            union { unsigned int u[4]; bf16x8 v; } af;
#pragma unroll
            for (int d = 0; d < 4; ++d) af.u[d] = pk_trunc(x[2 * d], x[2 * d + 1]);
            f32x4 a0 = (f32x4){vbm20, vbm20, vbm20, vbm20};
            f32x4 a1 = (f32x4){vbm21, vbm21, vbm21, vbm21};
            a0 = __builtin_amdgcn_mfma_f32_16x16x32_bf16(af.v, WB1c0, a0, 0, 0, 0);
            a1 = __builtin_amdgcn_mfma_f32_16x16x32_bf16(af.v, WB1c1, a1, 0, 0, 0);

            // phase 2: silu, stage UNGATED s tile (pi-packed bf16 pairs, trunc)
            float s0[4], s1[4];
#pragma unroll
            for (int j = 0; j < 4; ++j) {
                s0[j] = fsilu(a0[j]);
                s1[j] = fsilu(a1[j]);
                mb[((rg << 2) + j) * 20 + c] = pk_trunc(s0[j], s1[j]);
            }

            // phase 3: attz MFMA + z MFMAs from staged tile, gate/pw/aggregate
            union { uint4 u; bf16x8 v; } qa;
            qa.u = *(const uint4*)(mb + c * 20 + (rg << 2));
            f32x4 za = (f32x4){batt, batt, batt, batt};
            f32x4 z0 = (f32x4){0.f, 0.f, 0.f, 0.f};
            f32x4 z1 = (f32x4){0.f, 0.f, 0.f, 0.f};
            za = __builtin_amdgcn_mfma_f32_16x16x32_bf16(qa.v, WBac,  za, 0, 0, 0);
            z0 = __builtin_amdgcn_mfma_f32_16x16x32_bf16(qa.v, WBpc0, z0, 0, 0, 0);
            z1 = __builtin_amdgcn_mfma_f32_16x16x32_bf16(qa.v, WBpc1, z1, 0, 0, 0);
#pragma unroll
            for (int j = 0; j < 4; ++j) {
                const float att = fsigmoid(za[j]);
                aghc0 += att * s0[j];
                aghc1 += att * s1[j];
                const float q0 = fsilu(att * z0[j] + vbp10);
                const float q1 = fsilu(att * z1[j] + vbp11);
                const float pwp = q0 * vwp20 + q1 * vwp21;
                const float2 pn = spn[w][(tt << 4) + (rg << 2) + j];
                apx += pwp * pn.x;
                apy += pwp * pn.y;
            }
        }
    }

    // ---- epilogue: reductions + stores ----
    aghc0 += __shfl_xor(aghc0, 16); aghc0 += __shfl_xor(aghc0, 32);
    aghc1 += __shfl_xor(aghc1, 16); aghc1 += __shfl_xor(aghc1, 32);
#pragma unroll
    for (int off = 1; off < 64; off <<= 1) {
        apx  += __shfl_xor(apx, off);
        apy  += __shfl_xor(apy, off);
        spnx += __shfl_xor(spnx, off);
        spny += __shfl_xor(spny, off);
    }
    if (lane < 16)       aggh[dstNode * 32 + lane] = aghc0;
    else if (lane < 32)  aggh[dstNode * 32 + lane] = aghc1;
    if (lane == 0) {
        aggp[dstNode * 2]     = (apx + bp2 * spnx) * (1.0f / 128.0f);
        aggp[dstNode * 2 + 1] = (apy + bp2 * spny) * (1.0f / 128.0f);
    }
}

// ---------------- fused node update + pre(layer+1) ----------------
// thread = (node, channel); 1024 blocks x 256 thr; block = 8 nodes (one graph).
// temb update recomputed per block (trivial); one writer block per graph.
__global__ __launch_bounds__(256) void node_kernel(
    float* __restrict__ ws,
    const float* __restrict__ W_node1, const float* __restrict__ b_node1,
    const float* __restrict__ W_node2, const float* __restrict__ b_node2,
    const float* __restrict__ W_t, const float* __restrict__ b_t,
    const float* __restrict__ W_msg1, const float* __restrict__ b_msg1,
    int layer)
{
    __shared__ float sIn[8][64];    // h (0..31) | aggh (32..63) per local node
    __shared__ float sU1[8][32];
    __shared__ float sHn[8][32];
    __shared__ float sTold[32], sTnew[32];

    const int tid = blockIdx.x * 256 + threadIdx.x;   // (node, c)
    const int c = tid & 31;
    const int node = tid >> 5;
    const int ln = (threadIdx.x >> 5) & 7;
    const int g = node >> 7;

    const float* __restrict__ Wn1 = W_node1 + layer * 2048;
    const float* __restrict__ Wn2 = W_node2 + layer * 1024;

    sIn[ln][c]      = ws[OFF_H + node * 32 + c];
    sIn[ln][32 + c] = ws[OFF_AGH + node * 32 + c];
    if (threadIdx.x < 32)
        sTold[threadIdx.x] = ws[((layer & 1) ? OFF_TEMB1 : OFF_TEMB0) + g * 32 + threadIdx.x];
    __syncthreads();

    float acc = b_node1[layer * 32 + c];
#pragma unroll
    for (int k = 0; k < 32; ++k)
        acc += sIn[ln][k] * Wn1[k * 32 + c] + sIn[ln][32 + k] * Wn1[(32 + k) * 32 + c];
    sU1[ln][c] = fsilu(acc);
    if (threadIdx.x < 32) {                          // temb update (per-block recompute)
        const float* Wt = W_t + layer * 1024;
        float a2 = b_t[layer * 32 + threadIdx.x];
#pragma unroll
        for (int k = 0; k < 32; ++k) a2 += sTold[k] * Wt[k * 32 + threadIdx.x];
        sTnew[threadIdx.x] = fsilu(a2);
    }
    __syncthreads();

    float u = b_node2[layer * 32 + c];
#pragma unroll
    for (int k = 0; k < 32; ++k) u += sU1[ln][k] * Wn2[k * 32 + c];
    const float hn = (u > 0.f ? u : 0.01f * u) + sIn[ln][c];
    ws[OFF_H + node * 32 + c] = hn;
    sHn[ln][c] = hn;

    if (c < 2)                                       // p += aggr_p (2 lanes per node)
        ws[OFF_P + node * 2 + c] += ws[OFF_AGP + node * 2 + c];
    if ((blockIdx.x & 15) == 0 && threadIdx.x < 32)  // persist new temb (1 block/graph)
        ws[((layer & 1) ? OFF_TEMB0 : OFF_TEMB1) + g * 32 + threadIdx.x] = sTnew[threadIdx.x];
    __syncthreads();

    // fused pre for layer+1: HA (f32) + HBh (bf16) from hn, sTnew
    const float* __restrict__ W1 = W_msg1 + (layer + 1) * 97 * 32;
    float accA = b_msg1[(layer + 1) * 32 + c];
    float accB = 0.f;
#pragma unroll
    for (int k = 0; k < 32; ++k) {
        const float hk = sHn[ln][k];
        accA += hk * W1[k * 32 + c];
        accB += hk * W1[(32 + k) * 32 + c];
    }
#pragma unroll
    for (int k = 0; k < 32; ++k)
        accA += sTnew[k] * W1[(65 + k) * 32 + c];
    ws[OFF_HA + node * 32 + c] = accA;
    ((unsigned short*)(ws + OFF_HB))[node * 32 + c] = (unsigned short)f2bfs(accB);
}

// ---------------- final: p += aggr_p for shelves, emit fp32 ----------------
__global__ __launch_bounds__(256) void out_kernel(const float* __restrict__ R,
                                                  float* __restrict__ out)
{
    const int o = blockIdx.x * 256 + threadIdx.x;     // 0..14335
    if (o >= B * NSH * 2) return;
    const int d = o & 1;
    const int s = (o >> 1) % NSH;
    const int b = (o >> 1) / NSH;
    const int node = b * 128 + NG + s;
    out[o] = R[OFF_P + node * 2 + d] + R[OFF_AGP + node * 2 + d];
}

// ---------------- launch ----------------
extern "C" void kernel_launch(void* const* d_in, const int* in_sizes, int n_in,
                              void* d_out, int out_size, void* d_ws, size_t ws_size,
                              hipStream_t stream)
{
    const float* pos      = (const float*)d_in[0];
    const int*   tsteps   = (const int*)d_in[1];
    const float* goal_pos = (const float*)d_in[2];
    const float* W_hin    = (const float*)d_in[3];
    const float* b_hin    = (const float*)d_in[4];
    const float* W_msg1   = (const float*)d_in[5];
    const float* b_msg1   = (const float*)d_in[6];
    const float* W_msg2   = (const float*)d_in[7];
    const float* b_msg2   = (const float*)d_in[8];
    const float* W_att    = (const float*)d_in[9];
    const float* b_att    = (const float*)d_in[10];
    const float* W_pos1   = (const float*)d_in[11];
    const float* b_pos1   = (const float*)d_in[12];
    const float* W_pos2   = (const float*)d_in[13];
    const float* b_pos2   = (const float*)d_in[14];
    const float* W_node1  = (const float*)d_in[15];
    const float* b_node1  = (const float*)d_in[16];
    const float* W_node2  = (const float*)d_in[17];
    const float* b_node2  = (const float*)d_in[18];
    const float* W_t      = (const float*)d_in[19];
    const float* b_t      = (const float*)d_in[20];

    float* ws = (float*)d_ws;

    constexpr int setup_threads = NN * 32 + NN * 2 + B * 32;
    setup_kernel<<<(setup_threads + 255) / 256, 256, 0, stream>>>(
        pos, tsteps, goal_pos, W_hin, b_hin, ws);
    pre_kernel<<<NN * 32 / 256, 256, 0, stream>>>(ws, W_msg1, b_msg1, ws + OFF_TEMB0, 0);

    for (int l = 0; l < L; ++l) {
        edge_kernel<<<2048, 256, 0, stream>>>(ws, W_msg1, W_msg2, b_msg2, W_att, b_att,
                                              W_pos1, b_pos1, W_pos2, b_pos2,
                                              ws + OFF_AGH, ws + OFF_AGP, l);
        if (l < L - 1)
            node_kernel<<<NN * 32 / 256, 256, 0, stream>>>(ws, W_node1, b_node1, W_node2,
                                                           b_node2, W_t, b_t, W_msg1, b_msg1, l);
    }
    out_kernel<<<(B * NSH * 2 + 255) / 256, 256, 0, stream>>>(ws, (float*)d_out);
}

// Round 9
// 293.415 us; speedup vs baseline: 1.9155x; 1.0508x over previous
//
#include <hip/hip_runtime.h>
#include <hip/hip_bf16.h>

// ---------------- problem constants ----------------
constexpr int B = 64;
constexpr int NG = 16;
constexpr int NSH = 112;
constexpr int N = 128;          // nodes per graph
constexpr int NN = B * N;       // 8192 total nodes
constexpr int L = 5;

// ---------------- workspace layout (float offsets) ----------------
constexpr int OFF_H     = 0;                    // [8192][32] f32
constexpr int OFF_P     = OFF_H + NN * 32;      // [8192][2]  f32
constexpr int OFF_TEMB0 = OFF_P + NN * 2;       // [64][32]
constexpr int OFF_TEMB1 = OFF_TEMB0 + B * 32;
constexpr int OFF_HA    = OFF_TEMB1 + B * 32;   // [8192][32] f32 (h[dst]-term + temb-term + b_msg1)
constexpr int OFF_HB    = OFF_HA + NN * 32;     // [8192][32] stored as ushort bf16 (h[src]-term)
constexpr int OFF_AGH   = OFF_HB + NN * 32;     // [8192][32] f32
constexpr int OFF_AGP   = OFF_AGH + NN * 32;    // [8192][2]  f32

typedef __attribute__((ext_vector_type(8))) short bf16x8;
typedef __attribute__((ext_vector_type(4))) float f32x4;

// ---------------- math helpers ----------------
__device__ __forceinline__ float fsigmoid(float x) {
    return __builtin_amdgcn_rcpf(1.0f + __expf(-x));
}
__device__ __forceinline__ float fsilu(float x) { return x * fsigmoid(x); }
__device__ __forceinline__ short f2bfs(float f) {           // RNE (setup paths only)
    union { __hip_bfloat16 b; short s; } u; u.b = __float2bfloat16(f); return u.s;
}
__device__ __forceinline__ float bf2f(unsigned short u) {
    union { unsigned int i; float f; } v; v.i = ((unsigned int)u) << 16; return v.f;
}
// single-inst truncation pack: dst = bf16(hi)<<16 | bf16(lo)
__device__ __forceinline__ unsigned int pk_trunc(float lo, float hi) {
    union { float f; unsigned int u; } a, b;
    a.f = hi; b.f = lo;
    return __builtin_amdgcn_perm(a.u, b.u, 0x07060302u);
}

// ---------------- setup: init h / p / temb0 ----------------
__global__ __launch_bounds__(256) void setup_kernel(
    const float* __restrict__ pos, const int* __restrict__ timesteps,
    const float* __restrict__ goal_pos,
    const float* __restrict__ W_hin, const float* __restrict__ b_hin,
    float* __restrict__ ws)
{
    int idx = blockIdx.x * 256 + threadIdx.x;

    if (idx < NN * 32) {                       // h init: goals use W_hin row 0, shelves row 1
        int c = idx & 31; int node = idx >> 5; int local = node & 127;
        int row = (local < NG) ? 0 : 1;
        ws[OFF_H + idx] = W_hin[row * 32 + c] + b_hin[c];
        return;
    }
    idx -= NN * 32;
    if (idx < NN * 2) {                        // p init
        int d = idx & 1; int node = idx >> 1; int g = node >> 7; int local = node & 127;
        float v = (local < NG) ? goal_pos[local * 2 + d]
                               : pos[(g * NSH + (local - NG)) * 2 + d];
        ws[OFF_P + idx] = v;
        return;
    }
    idx -= NN * 2;
    if (idx < B * 32) {                        // sinusoidal timestep embedding
        int j = idx & 31; int g = idx >> 5;
        float t = (float)timesteps[g];
        int jj = (j < 16) ? j : (j - 16);
        float freq = expf(-logf(10000.0f) * (float)jj / 16.0f);
        float ang = t * freq;
        ws[OFF_TEMB0 + idx] = (j < 16) ? cosf(ang) : sinf(ang);
    }
}

// ---------------- layer-0 node precompute: HA (f32), HBh (bf16) ----------------
__global__ __launch_bounds__(256) void pre_kernel(
    float* __restrict__ R,
    const float* __restrict__ W_msg1, const float* __restrict__ b_msg1,
    const float* __restrict__ tembIn, int layer)
{
    int tid = blockIdx.x * 256 + threadIdx.x;   // 0 .. 262143
    int c = tid & 31; int node = tid >> 5; int g = node >> 7;
    const float* __restrict__ W1 = W_msg1 + layer * 97 * 32;
    float accA = b_msg1[layer * 32 + c];
    float accB = 0.f;
#pragma unroll
    for (int k = 0; k < 32; ++k) {
        float hk = R[OFF_H + node * 32 + k];
        accA += hk * W1[k * 32 + c];
        accB += hk * W1[(32 + k) * 32 + c];
    }
#pragma unroll
    for (int k = 0; k < 32; ++k)
        accA += tembIn[g * 32 + k] * W1[(65 + k) * 32 + c];
    R[OFF_HA + tid] = accA;
    ((unsigned short*)(R + OFF_HB))[tid] = (unsigned short)f2bfs(accB);
}

// ---------------- edge kernel (MFMA): messages + gated aggregation ----------------
// grid: 64 graphs x 32 dst-groups = 2048 blocks, 256 thr = 4 waves.
// Per-tile fused pipeline. waves_per_eu(2,4): proven no-spill config.
// Layer L-1: writes final shelf positions directly to out (out_kernel fused).
__global__ __attribute__((amdgpu_flat_work_group_size(256, 256)))
__attribute__((amdgpu_waves_per_eu(2, 4))) void edge_kernel(
    float* __restrict__ R,
    const float* __restrict__ W_msg1,
    const float* __restrict__ W_msg2, const float* __restrict__ b_msg2,
    const float* __restrict__ W_att, const float* __restrict__ b_att,
    const float* __restrict__ W_pos1, const float* __restrict__ b_pos1,
    const float* __restrict__ W_pos2, const float* __restrict__ b_pos2,
    float* __restrict__ aggh, float* __restrict__ aggp,
    float* __restrict__ out, int layer)
{
    __shared__ unsigned short sHBh[128 * 40];   // bf16, row stride 40 (80B, 16B-aligned)
    __shared__ float sPx[128], sPy[128];
    __shared__ unsigned int mbuf[4 * 16 * 20];  // per-wave 16-row tile staging (reused per tt)
    __shared__ float2 spn[4][64];               // per-wave (pnx,pny) row-broadcast buffer

    const int t = threadIdx.x;
    const int bx = blockIdx.x;
    const int g = bx >> 5;
    const int gbase = g * 128;

    // ---- stage HBh (graph's 128x32 bf16) + positions ----
    const unsigned short* HBH = (const unsigned short*)(R + OFF_HB);
#pragma unroll
    for (int ch = 0; ch < 2; ++ch) {
        int chunk = t + ch * 256;               // 512 chunks of 8 bf16
        int row = chunk >> 2, g4 = chunk & 3;
        uint4 v = *(const uint4*)(HBH + (gbase + row) * 32 + (g4 << 3));
        *(uint4*)(sHBh + row * 40 + (g4 << 3)) = v;
    }
    if (t < 128) {
        sPx[t] = R[OFF_P + (gbase + t) * 2];
        sPy[t] = R[OFF_P + (gbase + t) * 2 + 1];
    }
    __syncthreads();

    const int lane = t & 63, w = t >> 6;
    const int c = lane & 15;
    const int rg = lane >> 4;
    const int kk = rg << 3;
    const int dloc = ((bx & 31) << 2) | w;
    const int dstNode = gbase + dloc;

    // ---- resident weight fragments (bf16, RNE one-time) ----
    const float* __restrict__ Wm2L = W_msg2 + layer * 1024;
    const float* __restrict__ Wp1L = W_pos1 + layer * 1024;
    bf16x8 WB1c0, WB1c1, WBpc0, WBpc1, WBac;
#pragma unroll
    for (int j = 0; j < 8; ++j) {
        WB1c0[j] = f2bfs(Wm2L[(kk + j) * 32 + c]);
        WB1c1[j] = f2bfs(Wm2L[(kk + j) * 32 + c + 16]);
        int pk = ((kk + j) & 1) * 16 + ((kk + j) >> 1);   // pi-permuted k for staged A
        WBpc0[j] = f2bfs(Wp1L[pk * 32 + c]);
        WBpc1[j] = f2bfs(Wp1L[pk * 32 + c + 16]);
        WBac[j]  = f2bfs(W_att[layer * 32 + pk]);         // column-replicated
    }

    // ---- per-dst / per-lane constants ----
    float vha[8], vwr[8];
    {
        const float* haR = R + OFF_HA + dstNode * 32 + kk;
        const float* wrR = W_msg1 + layer * 97 * 32 + 64 * 32 + kk;
#pragma unroll
        for (int j = 0; j < 8; ++j) { vha[j] = haR[j]; vwr[j] = wrR[j]; }
    }
    const float batt   = b_att[layer];
    const float vbm20  = b_msg2[layer * 32 + c], vbm21 = b_msg2[layer * 32 + c + 16];
    const float vbp10  = b_pos1[layer * 32 + c], vbp11 = b_pos1[layer * 32 + c + 16];
    const float vwp20  = W_pos2[layer * 32 + c], vwp21 = W_pos2[layer * 32 + c + 16];
    const float bp2    = b_pos2[layer];
    const float pxd = R[OFF_P + dstNode * 2], pyd = R[OFF_P + dstNode * 2 + 1];

    unsigned int* mb = mbuf + w * 16 * 20;

    float aghc0 = 0.f, aghc1 = 0.f, apx = 0.f, apy = 0.f, spnx = 0.f, spny = 0.f;

#pragma unroll 1
    for (int half = 0; half < 2; ++half) {
        // ---- per-src geometry (lane = src within half) ----
        const int src = (half << 6) + lane;
        const float dx = pxd - sPx[src];
        const float dy = pyd - sPy[src];
        const float radial = dx * dx + dy * dy;
        const float inv = __builtin_amdgcn_rcpf(__builtin_amdgcn_sqrtf(radial) + 1e-6f);
        const float pnx = dx * inv, pny = dy * inv;
        spnx += pnx; spny += pny;
        spn[w][lane] = (float2){pnx, pny};

        // ---- fused per-tile pipeline: 16 edge rows at a time ----
#pragma unroll
        for (int tt = 0; tt < 4; ++tt) {
            // phase 1: build m1 A-frag (trunc pack), GEMM-1
            const float rad_t = __shfl(radial, c + (tt << 4));
            uint4 hraw = *(const uint4*)(sHBh + ((half << 6) + c + (tt << 4)) * 40 + kk);
            const unsigned short* hs = (const unsigned short*)&hraw;
            float x[8];
#pragma unroll
            for (int j = 0; j < 8; ++j)
                x[j] = fsilu(vha[j] + bf2f(hs[j]) + rad_t * vwr[j]);
            union { unsigned int u[4]; bf16x8 v; } af;
#pragma unroll
            for (int d = 0; d < 4; ++d) af.u[d] = pk_trunc(x[2 * d], x[2 * d + 1]);
            f32x4 a0 = (f32x4){vbm20, vbm20, vbm20, vbm20};
            f32x4 a1 = (f32x4){vbm21, vbm21, vbm21, vbm21};
            a0 = __builtin_amdgcn_mfma_f32_16x16x32_bf16(af.v, WB1c0, a0, 0, 0, 0);
            a1 = __builtin_amdgcn_mfma_f32_16x16x32_bf16(af.v, WB1c1, a1, 0, 0, 0);

            // phase 2: silu, stage UNGATED s tile (pi-packed bf16 pairs, trunc)
            float s0[4], s1[4];
#pragma unroll
            for (int j = 0; j < 4; ++j) {
                s0[j] = fsilu(a0[j]);
                s1[j] = fsilu(a1[j]);
                mb[((rg << 2) + j) * 20 + c] = pk_trunc(s0[j], s1[j]);
            }

            // phase 3: attz MFMA + z MFMAs from staged tile, gate/pw/aggregate
            union { uint4 u; bf16x8 v; } qa;
            qa.u = *(const uint4*)(mb + c * 20 + (rg << 2));
            f32x4 za = (f32x4){batt, batt, batt, batt};
            f32x4 z0 = (f32x4){0.f, 0.f, 0.f, 0.f};
            f32x4 z1 = (f32x4){0.f, 0.f, 0.f, 0.f};
            za = __builtin_amdgcn_mfma_f32_16x16x32_bf16(qa.v, WBac,  za, 0, 0, 0);
            z0 = __builtin_amdgcn_mfma_f32_16x16x32_bf16(qa.v, WBpc0, z0, 0, 0, 0);
            z1 = __builtin_amdgcn_mfma_f32_16x16x32_bf16(qa.v, WBpc1, z1, 0, 0, 0);
#pragma unroll
            for (int j = 0; j < 4; ++j) {
                const float att = fsigmoid(za[j]);
                aghc0 += att * s0[j];
                aghc1 += att * s1[j];
                const float q0 = fsilu(att * z0[j] + vbp10);
                const float q1 = fsilu(att * z1[j] + vbp11);
                const float pwp = q0 * vwp20 + q1 * vwp21;
                const float2 pn = spn[w][(tt << 4) + (rg << 2) + j];
                apx += pwp * pn.x;
                apy += pwp * pn.y;
            }
        }
    }

    // ---- epilogue: reductions + stores ----
    aghc0 += __shfl_xor(aghc0, 16); aghc0 += __shfl_xor(aghc0, 32);
    aghc1 += __shfl_xor(aghc1, 16); aghc1 += __shfl_xor(aghc1, 32);
#pragma unroll
    for (int off = 1; off < 64; off <<= 1) {
        apx  += __shfl_xor(apx, off);
        apy  += __shfl_xor(apy, off);
        spnx += __shfl_xor(spnx, off);
        spny += __shfl_xor(spny, off);
    }
    if (layer < L - 1) {
        if (lane < 16)       aggh[dstNode * 32 + lane] = aghc0;
        else if (lane < 32)  aggh[dstNode * 32 + lane] = aghc1;
        if (lane == 0) {
            aggp[dstNode * 2]     = (apx + bp2 * spnx) * (1.0f / 128.0f);
            aggp[dstNode * 2 + 1] = (apy + bp2 * spny) * (1.0f / 128.0f);
        }
    } else if (lane == 0 && dloc >= NG) {           // final layer: write shelf output
        out[(g * NSH + (dloc - NG)) * 2]     = pxd + (apx + bp2 * spnx) * (1.0f / 128.0f);
        out[(g * NSH + (dloc - NG)) * 2 + 1] = pyd + (apy + bp2 * spny) * (1.0f / 128.0f);
    }
}

// ---------------- fused node update + pre(layer+1), MFMA version ----------------
// 512 blocks x 64 thr (1 wave = 16 nodes; 8 blocks per graph). Uses the verified
// edge layout conventions: A[m=lane&15][k=rg*8+j], C col=lane&15 row=rg*4+j,
// pi-packed LDS round-trip for C->A. Residual h kept f32 (only MFMA inputs bf16).
__global__ __attribute__((amdgpu_flat_work_group_size(64, 64)))
__attribute__((amdgpu_waves_per_eu(2, 4))) void node_kernel(
    float* __restrict__ ws,
    const float* __restrict__ W_node1, const float* __restrict__ b_node1,
    const float* __restrict__ W_node2, const float* __restrict__ b_node2,
    const float* __restrict__ W_t, const float* __restrict__ b_t,
    const float* __restrict__ W_msg1, const float* __restrict__ b_msg1,
    int layer)
{
    __shared__ float sH[16][36];    // f32 h rows (stride 36: 16B-aligned b128 reads)
    __shared__ float sAG[16][36];
    __shared__ unsigned int mb[16 * 20];  // pi-packed staging (stride 20, edge-proven)

    const int lane = threadIdx.x;          // single wave
    const int bx = blockIdx.x;             // 0..511
    const int nbase = bx << 4;
    const int g = bx >> 3;
    const int c = lane & 15, rg = lane >> 4, kk = rg << 3;

    // ---- stage h / aggh (16 rows x 32 f32 each), coalesced ----
    {
        const int row = lane >> 2, seg = lane & 3;
        const float* hsrc = ws + OFF_H + (nbase + row) * 32 + (seg << 3);
        const float* asrc = ws + OFF_AGH + (nbase + row) * 32 + (seg << 3);
#pragma unroll
        for (int j = 0; j < 8; ++j) {
            sH[row][(seg << 3) + j]  = hsrc[j];
            sAG[row][(seg << 3) + j] = asrc[j];
        }
    }
    // single-wave block: DS ops are in-order within the wave, no barrier needed

    // ---- resident B fragments ----
    const float* __restrict__ Wn1 = W_node1 + layer * 2048;
    const float* __restrict__ Wn2 = W_node2 + layer * 1024;
    const float* __restrict__ W1  = W_msg1 + (layer + 1) * 97 * 32;
    bf16x8 B1[2][2], B2[2], Ba[2], Bb[2];
#pragma unroll
    for (int j = 0; j < 8; ++j) {
        const int pk = ((kk + j) & 1) * 16 + ((kk + j) >> 1);
#pragma unroll
        for (int nh = 0; nh < 2; ++nh) {
            B1[0][nh][j] = f2bfs(Wn1[(kk + j) * 32 + nh * 16 + c]);        // k-half 0 (h)
            B1[1][nh][j] = f2bfs(Wn1[(32 + kk + j) * 32 + nh * 16 + c]);   // k-half 1 (aggh)
            B2[nh][j]    = f2bfs(Wn2[pk * 32 + nh * 16 + c]);              // pi-ordered
            Ba[nh][j]    = f2bfs(W1[pk * 32 + nh * 16 + c]);               // HA (h-rows)
            Bb[nh][j]    = f2bfs(W1[(32 + pk) * 32 + nh * 16 + c]);        // HB
        }
    }

    // ---- temb chain (redundant per block; uniform loads scalarize) ----
    const int c2 = lane & 31;
    const float* __restrict__ tin = ws + ((layer & 1) ? OFF_TEMB1 : OFF_TEMB0) + g * 32;
    const float* __restrict__ Wt = W_t + layer * 1024;
    float a2 = b_t[layer * 32 + c2];
#pragma unroll
    for (int k = 0; k < 32; ++k) a2 += tin[k] * Wt[k * 32 + c2];
    const float tnew = fsilu(a2);
    float tv = b_msg1[(layer + 1) * 32 + c2];
#pragma unroll
    for (int k = 0; k < 32; ++k) tv += __shfl(tnew, k) * W1[(65 + k) * 32 + c2];
    if ((bx & 7) == 0 && lane < 32)
        ws[((layer & 1) ? OFF_TEMB0 : OFF_TEMB1) + g * 32 + lane] = tnew;

    // ---- GEMM1: [h|aggh] (16x64) @ Wn1 -> u1 (16x32) ----
    union { unsigned int u[4]; bf16x8 v; } A0, A1;
#pragma unroll
    for (int d = 0; d < 4; ++d) {
        A0.u[d] = pk_trunc(sH[c][kk + 2 * d],  sH[c][kk + 2 * d + 1]);
        A1.u[d] = pk_trunc(sAG[c][kk + 2 * d], sAG[c][kk + 2 * d + 1]);
    }
    f32x4 u1[2];
#pragma unroll
    for (int nh = 0; nh < 2; ++nh) {
        const float bb = b_node1[layer * 32 + nh * 16 + c];
        f32x4 acc = (f32x4){bb, bb, bb, bb};
        acc = __builtin_amdgcn_mfma_f32_16x16x32_bf16(A0.v, B1[0][nh], acc, 0, 0, 0);
        acc = __builtin_amdgcn_mfma_f32_16x16x32_bf16(A1.v, B1[1][nh], acc, 0, 0, 0);
        u1[nh] = acc;
    }

    // ---- silu + pi-stage u1, GEMM2 -> u2 ----
#pragma unroll
    for (int j = 0; j < 4; ++j)
        mb[((rg << 2) + j) * 20 + c] = pk_trunc(fsilu(u1[0][j]), fsilu(u1[1][j]));
    union { uint4 q; bf16x8 v; } qa;
    qa.q = *(const uint4*)(mb + c * 20 + (rg << 2));
    f32x4 u2[2];
#pragma unroll
    for (int nh = 0; nh < 2; ++nh) {
        const float bb = b_node2[layer * 32 + nh * 16 + c];
        f32x4 acc = (f32x4){bb, bb, bb, bb};
        u2[nh] = __builtin_amdgcn_mfma_f32_16x16x32_bf16(qa.v, B2[nh], acc, 0, 0, 0);
    }

    // ---- h' = leaky(u2) + h (f32 residual), store + pi-stage for pre ----
    float hp0[4], hp1[4];
#pragma unroll
    for (int j = 0; j < 4; ++j) {
        const int row = (rg << 2) + j;
        const float h0 = sH[row][c], h1 = sH[row][c + 16];
        const float v0 = u2[0][j], v1 = u2[1][j];
        hp0[j] = (v0 > 0.f ? v0 : 0.01f * v0) + h0;
        hp1[j] = (v1 > 0.f ? v1 : 0.01f * v1) + h1;
        ws[OFF_H + (nbase + row) * 32 + c]      = hp0[j];
        ws[OFF_H + (nbase + row) * 32 + c + 16] = hp1[j];
        mb[row * 20 + c] = pk_trunc(hp0[j], hp1[j]);
    }

    // ---- fused pre(layer+1): HA / HB via MFMA ----
    qa.q = *(const uint4*)(mb + c * 20 + (rg << 2));
    f32x4 ha[2], hb[2];
    {
        f32x4 zz = (f32x4){0.f, 0.f, 0.f, 0.f};
#pragma unroll
        for (int nh = 0; nh < 2; ++nh) {
            ha[nh] = __builtin_amdgcn_mfma_f32_16x16x32_bf16(qa.v, Ba[nh], zz, 0, 0, 0);
            hb[nh] = __builtin_amdgcn_mfma_f32_16x16x32_bf16(qa.v, Bb[nh], zz, 0, 0, 0);
        }
    }
    const float tv0 = __shfl(tv, c), tv1 = __shfl(tv, c + 16);
    unsigned short* HBH = (unsigned short*)(ws + OFF_HB);
#pragma unroll
    for (int j = 0; j < 4; ++j) {
        const int node = nbase + (rg << 2) + j;
        ws[OFF_HA + node * 32 + c]      = ha[0][j] + tv0;
        ws[OFF_HA + node * 32 + c + 16] = ha[1][j] + tv1;
        HBH[node * 32 + c]      = (unsigned short)f2bfs(hb[0][j]);
        HBH[node * 32 + c + 16] = (unsigned short)f2bfs(hb[1][j]);
    }

    // ---- p += aggr_p (16 nodes x 2 dims on lanes 0..31) ----
    if (lane < 32) {
        const int node = nbase + (lane >> 1), d = lane & 1;
        ws[OFF_P + node * 2 + d] += ws[OFF_AGP + node * 2 + d];
    }
}

// ---------------- launch ----------------
extern "C" void kernel_launch(void* const* d_in, const int* in_sizes, int n_in,
                              void* d_out, int out_size, void* d_ws, size_t ws_size,
                              hipStream_t stream)
{
    const float* pos      = (const float*)d_in[0];
    const int*   tsteps   = (const int*)d_in[1];
    const float* goal_pos = (const float*)d_in[2];
    const float* W_hin    = (const float*)d_in[3];
    const float* b_hin    = (const float*)d_in[4];
    const float* W_msg1   = (const float*)d_in[5];
    const float* b_msg1   = (const float*)d_in[6];
    const float* W_msg2   = (const float*)d_in[7];
    const float* b_msg2   = (const float*)d_in[8];
    const float* W_att    = (const float*)d_in[9];
    const float* b_att    = (const float*)d_in[10];
    const float* W_pos1   = (const float*)d_in[11];
    const float* b_pos1   = (const float*)d_in[12];
    const float* W_pos2   = (const float*)d_in[13];
    const float* b_pos2   = (const float*)d_in[14];
    const float* W_node1  = (const float*)d_in[15];
    const float* b_node1  = (const float*)d_in[16];
    const float* W_node2  = (const float*)d_in[17];
    const float* b_node2  = (const float*)d_in[18];
    const float* W_t      = (const float*)d_in[19];
    const float* b_t      = (const float*)d_in[20];

    float* ws = (float*)d_ws;

    constexpr int setup_threads = NN * 32 + NN * 2 + B * 32;
    setup_kernel<<<(setup_threads + 255) / 256, 256, 0, stream>>>(
        pos, tsteps, goal_pos, W_hin, b_hin, ws);
    pre_kernel<<<NN * 32 / 256, 256, 0, stream>>>(ws, W_msg1, b_msg1, ws + OFF_TEMB0, 0);

    for (int l = 0; l < L; ++l) {
        edge_kernel<<<2048, 256, 0, stream>>>(ws, W_msg1, W_msg2, b_msg2, W_att, b_att,
                                              W_pos1, b_pos1, W_pos2, b_pos2,
                                              ws + OFF_AGH, ws + OFF_AGP,
                                              (float*)d_out, l);
        if (l < L - 1)
            node_kernel<<<512, 64, 0, stream>>>(ws, W_node1, b_node1, W_node2,
                                                b_node2, W_t, b_t, W_msg1, b_msg1, l);
    }
}

// Round 12
// 286.862 us; speedup vs baseline: 1.9593x; 1.0228x over previous
//
#include <hip/hip_runtime.h>
#include <hip/hip_bf16.h>

// ---------------- problem constants ----------------
constexpr int B = 64;
constexpr int NG = 16;
constexpr int NSH = 112;
constexpr int N = 128;          // nodes per graph
constexpr int NN = B * N;       // 8192 total nodes
constexpr int L = 5;

// ---------------- workspace layout (float offsets), double-buffered ----------------
constexpr int OFF_H     = 0;                    // [8192][32] f32 (owner-block access only)
constexpr int OFF_P0    = OFF_H + NN * 32;      // [8192][2]  f32
constexpr int OFF_P1    = OFF_P0 + NN * 2;
constexpr int OFF_TEMB0 = OFF_P1 + NN * 2;      // [64][32]
constexpr int OFF_TEMB1 = OFF_TEMB0 + B * 32;
constexpr int OFF_HA0   = OFF_TEMB1 + B * 32;   // [8192][32] f32
constexpr int OFF_HA1   = OFF_HA0 + NN * 32;
constexpr int OFF_HB0   = OFF_HA1 + NN * 32;    // [8192][32] ushort bf16 (NN*16 floats)
constexpr int OFF_HB1   = OFF_HB0 + NN * 16;

typedef __attribute__((ext_vector_type(8))) short bf16x8;
typedef __attribute__((ext_vector_type(4))) float f32x4;

// ---------------- math helpers ----------------
__device__ __forceinline__ float fsigmoid(float x) {
    return __builtin_amdgcn_rcpf(1.0f + __expf(-x));
}
__device__ __forceinline__ float fsilu(float x) { return x * fsigmoid(x); }
__device__ __forceinline__ short f2bfs(float f) {           // RNE
    union { __hip_bfloat16 b; short s; } u; u.b = __float2bfloat16(f); return u.s;
}
__device__ __forceinline__ float bf2f(unsigned short u) {
    union { unsigned int i; float f; } v; v.i = ((unsigned int)u) << 16; return v.f;
}
// single-inst truncation pack: dst = bf16(hi)<<16 | bf16(lo)
__device__ __forceinline__ unsigned int pk_trunc(float lo, float hi) {
    union { float f; unsigned int u; } a, b;
    a.f = hi; b.f = lo;
    return __builtin_amdgcn_perm(a.u, b.u, 0x07060302u);
}

// ---------------- setup + pre(layer 0): h, p, temb0, HA0, HB0 ----------------
// 1024 blocks x 256 thr; block = 8 nodes of one graph.
__global__ __launch_bounds__(256) void setup_pre_kernel(
    float* __restrict__ ws,
    const float* __restrict__ pos, const int* __restrict__ tsteps,
    const float* __restrict__ goal_pos,
    const float* __restrict__ W_hin, const float* __restrict__ b_hin,
    const float* __restrict__ W_msg1, const float* __restrict__ b_msg1)
{
    __shared__ float sT[32];
    const int t = threadIdx.x, bx = blockIdx.x;
    const int tid = bx * 256 + t;              // 0..262143 == NN*32
    const int c = tid & 31, node = tid >> 5, g = node >> 7, local = node & 127;
    const int row = (local < NG) ? 0 : 1;

    if (t < 32) {                              // temb for this block's graph
        const float tf = (float)tsteps[g];
        const int jj = (t < 16) ? t : (t - 16);
        const float ang = tf * expf(-logf(10000.0f) * (float)jj / 16.0f);
        sT[t] = (t < 16) ? cosf(ang) : sinf(ang);
    }
    __syncthreads();
    if ((bx & 15) == 0 && t < 32) ws[OFF_TEMB0 + g * 32 + t] = sT[t];

    ws[OFF_H + tid] = W_hin[row * 32 + c] + b_hin[c];     // h init

    if (tid < NN * 2) {                        // p init -> P0
        const int d = tid & 1, nd = tid >> 1, g0 = nd >> 7, loc = nd & 127;
        ws[OFF_P0 + tid] = (loc < NG) ? goal_pos[loc * 2 + d]
                                      : pos[(g0 * NSH + (loc - NG)) * 2 + d];
    }

    // pre layer 0 (h is type-determined: W_hin row + b_hin)
    const float* __restrict__ W1 = W_msg1;
    float accA = b_msg1[c], accB = 0.f;
#pragma unroll
    for (int k = 0; k < 32; ++k) {
        const float hk = W_hin[row * 32 + k] + b_hin[k];
        accA += hk * W1[k * 32 + c];
        accB += hk * W1[(32 + k) * 32 + c];
    }
#pragma unroll
    for (int k = 0; k < 32; ++k)
        accA += sT[k] * W1[(65 + k) * 32 + c];
    ws[OFF_HA0 + tid] = accA;
    ((unsigned short*)(ws + OFF_HB0))[tid] = (unsigned short)f2bfs(accB);
}

// ---------------- fused edge + node + pre(l+1) kernel ----------------
// 512 blocks x 256 thr; block = (graph, 16 dsts), 4 sub-iters of 4 dsts/wave.
// Reads parity l&1 buffers (HA/HB/P); node epilogue (single wave, R9-verified
// MFMA body) writes parity (l+1)&1 — no cross-block race within a dispatch.
// aggh/aggp pass through LDS only. Layer L-1 writes final shelf out directly.
__global__ __attribute__((amdgpu_flat_work_group_size(256, 256)))
__attribute__((amdgpu_waves_per_eu(2, 4))) void edge_kernel(
    float* __restrict__ ws,
    const float* __restrict__ W_msg1, const float* __restrict__ b_msg1,
    const float* __restrict__ W_msg2, const float* __restrict__ b_msg2,
    const float* __restrict__ W_att, const float* __restrict__ b_att,
    const float* __restrict__ W_pos1, const float* __restrict__ b_pos1,
    const float* __restrict__ W_pos2, const float* __restrict__ b_pos2,
    const float* __restrict__ W_node1, const float* __restrict__ b_node1,
    const float* __restrict__ W_node2, const float* __restrict__ b_node2,
    const float* __restrict__ W_t, const float* __restrict__ b_t,
    float* __restrict__ out, int l)
{
    __shared__ unsigned short sHBh[128 * 40];   // 10240 B
    __shared__ float sPx[128], sPy[128];        // 1024 B
    __shared__ __align__(16) unsigned char uraw[7168];  // edge: mbuf+spn / node: sH+nmb
    __shared__ float sAgg[16][36];              // 2304 B (live across the barrier)
    __shared__ float2 sAgp[16];                 // 128 B

    unsigned int* mbuf = (unsigned int*)uraw;            // 4*16*20*4 = 5120 B
    float2* spn = (float2*)(uraw + 5120);                // 4*64*8 = 2048 B
    float (*sH)[36] = (float(*)[36])uraw;                // node alias: 2304 B
    unsigned int* nmb = (unsigned int*)(uraw + 2304);    // node alias: 1280 B

    const int t = threadIdx.x;
    const int bx = blockIdx.x;                 // 0..511
    const int g = bx >> 3, qp = bx & 7;
    const int gbase = g << 7;
    const int par = l & 1, op = (l + 1) & 1;

    const float* __restrict__ HAin = ws + (par ? OFF_HA1 : OFF_HA0);
    const unsigned short* __restrict__ HBin = (const unsigned short*)(ws + (par ? OFF_HB1 : OFF_HB0));
    const float* __restrict__ Pin = ws + (par ? OFF_P1 : OFF_P0);

    // ---- stage HBh + positions ----
#pragma unroll
    for (int ch = 0; ch < 2; ++ch) {
        const int chunk = t + (ch << 8);
        const int row = chunk >> 2, g4 = chunk & 3;
        *(uint4*)(sHBh + row * 40 + (g4 << 3)) =
            *(const uint4*)(HBin + (gbase + row) * 32 + (g4 << 3));
    }
    if (t < 128) {
        sPx[t] = Pin[(gbase + t) * 2];
        sPy[t] = Pin[(gbase + t) * 2 + 1];
    }
    __syncthreads();

    const int lane = t & 63, w = t >> 6;
    const int c = lane & 15, rg = lane >> 4, kk = rg << 3;

    // ---- resident weight fragments ----
    const float* __restrict__ Wm2L = W_msg2 + l * 1024;
    const float* __restrict__ Wp1L = W_pos1 + l * 1024;
    bf16x8 WB1c0, WB1c1, WBpc0, WBpc1, WBac;
#pragma unroll
    for (int j = 0; j < 8; ++j) {
        WB1c0[j] = f2bfs(Wm2L[(kk + j) * 32 + c]);
        WB1c1[j] = f2bfs(Wm2L[(kk + j) * 32 + c + 16]);
        const int pk = ((kk + j) & 1) * 16 + ((kk + j) >> 1);
        WBpc0[j] = f2bfs(Wp1L[pk * 32 + c]);
        WBpc1[j] = f2bfs(Wp1L[pk * 32 + c + 16]);
        WBac[j]  = f2bfs(W_att[l * 32 + pk]);
    }
    float vwr[8];
    {
        const float* wrR = W_msg1 + l * 97 * 32 + 64 * 32 + kk;
#pragma unroll
        for (int j = 0; j < 8; ++j) vwr[j] = wrR[j];
    }
    const float batt  = b_att[l];
    const float vbm20 = b_msg2[l * 32 + c], vbm21 = b_msg2[l * 32 + c + 16];
    const float vbp10 = b_pos1[l * 32 + c], vbp11 = b_pos1[l * 32 + c + 16];
    const float vwp20 = W_pos2[l * 32 + c], vwp21 = W_pos2[l * 32 + c + 16];
    const float bp2   = b_pos2[l];

    unsigned int* mb = mbuf + w * 16 * 20;

#pragma unroll 1
    for (int si = 0; si < 4; ++si) {
        const int dl = (si << 2) + w;          // 0..15 local dst
        const int dloc = (qp << 4) + dl;
        const int dstNode = gbase + dloc;
        float vha[8];
        {
            const float* haR = HAin + dstNode * 32 + kk;
#pragma unroll
            for (int j = 0; j < 8; ++j) vha[j] = haR[j];
        }
        const float pxd = sPx[dloc], pyd = sPy[dloc];

        float aghc0 = 0.f, aghc1 = 0.f, apx = 0.f, apy = 0.f;
        float spnx = 0.f, spny = 0.f;

#pragma unroll 1
        for (int half = 0; half < 2; ++half) {
            const int src = (half << 6) + lane;
            const float dx = pxd - sPx[src];
            const float dy = pyd - sPy[src];
            const float radial = dx * dx + dy * dy;
            const float inv = __builtin_amdgcn_rcpf(__builtin_amdgcn_sqrtf(radial) + 1e-6f);
            const float pnx = dx * inv, pny = dy * inv;
            spnx += pnx; spny += pny;
            spn[w * 64 + lane] = (float2){pnx, pny};

#pragma unroll
            for (int tt = 0; tt < 4; ++tt) {
                // phase 1: m1 A-frag + GEMM-1
                const float rad_t = __shfl(radial, c + (tt << 4));
                uint4 hraw = *(const uint4*)(sHBh + ((half << 6) + c + (tt << 4)) * 40 + kk);
                const unsigned short* hs = (const unsigned short*)&hraw;
                float x[8];
#pragma unroll
                for (int j = 0; j < 8; ++j)
                    x[j] = fsilu(vha[j] + bf2f(hs[j]) + rad_t * vwr[j]);
                union { unsigned int u[4]; bf16x8 v; } af;
#pragma unroll
                for (int d = 0; d < 4; ++d) af.u[d] = pk_trunc(x[2 * d], x[2 * d + 1]);
                f32x4 a0 = (f32x4){vbm20, vbm20, vbm20, vbm20};
                f32x4 a1 = (f32x4){vbm21, vbm21, vbm21, vbm21};
                a0 = __builtin_amdgcn_mfma_f32_16x16x32_bf16(af.v, WB1c0, a0, 0, 0, 0);
                a1 = __builtin_amdgcn_mfma_f32_16x16x32_bf16(af.v, WB1c1, a1, 0, 0, 0);

                // phase 2: silu + pi-stage ungated s
                float s0[4], s1[4];
#pragma unroll
                for (int j = 0; j < 4; ++j) {
                    s0[j] = fsilu(a0[j]);
                    s1[j] = fsilu(a1[j]);
                    mb[((rg << 2) + j) * 20 + c] = pk_trunc(s0[j], s1[j]);
                }

                // phase 3: attz/z MFMAs, gate, pw, aggregate
                union { uint4 u; bf16x8 v; } qa;
                qa.u = *(const uint4*)(mb + c * 20 + (rg << 2));
                f32x4 za = (f32x4){batt, batt, batt, batt};
                f32x4 z0 = (f32x4){0.f, 0.f, 0.f, 0.f};
                f32x4 z1 = (f32x4){0.f, 0.f, 0.f, 0.f};
                za = __builtin_amdgcn_mfma_f32_16x16x32_bf16(qa.v, WBac,  za, 0, 0, 0);
                z0 = __builtin_amdgcn_mfma_f32_16x16x32_bf16(qa.v, WBpc0, z0, 0, 0, 0);
                z1 = __builtin_amdgcn_mfma_f32_16x16x32_bf16(qa.v, WBpc1, z1, 0, 0, 0);
#pragma unroll
                for (int j = 0; j < 4; ++j) {
                    const float att = fsigmoid(za[j]);
                    aghc0 += att * s0[j];
                    aghc1 += att * s1[j];
                    const float q0 = fsilu(att * z0[j] + vbp10);
                    const float q1 = fsilu(att * z1[j] + vbp11);
                    const float pwp = q0 * vwp20 + q1 * vwp21;
                    const float2 pn = spn[w * 64 + (tt << 4) + (rg << 2) + j];
                    apx += pwp * pn.x;
                    apy += pwp * pn.y;
                }
            }
        }

        // sub-iter epilogue: reduce, stash aggh/aggp in LDS (or write out at l=L-1)
        aghc0 += __shfl_xor(aghc0, 16); aghc0 += __shfl_xor(aghc0, 32);
        aghc1 += __shfl_xor(aghc1, 16); aghc1 += __shfl_xor(aghc1, 32);
#pragma unroll
        for (int off = 1; off < 64; off <<= 1) {
            apx  += __shfl_xor(apx, off);
            apy  += __shfl_xor(apy, off);
            spnx += __shfl_xor(spnx, off);
            spny += __shfl_xor(spny, off);
        }
        if (l < L - 1) {
            if (lane < 32) sAgg[dl][lane] = (lane < 16) ? aghc0 : aghc1;
            if (lane == 0)
                sAgp[dl] = (float2){(apx + bp2 * spnx) * (1.0f / 128.0f),
                                    (apy + bp2 * spny) * (1.0f / 128.0f)};
        } else if (lane == 0 && dloc >= NG) {
            out[(g * NSH + (dloc - NG)) * 2]     = pxd + (apx + bp2 * spnx) * (1.0f / 128.0f);
            out[(g * NSH + (dloc - NG)) * 2 + 1] = pyd + (apy + bp2 * spny) * (1.0f / 128.0f);
        }
    }
    if (l == L - 1) return;

    __syncthreads();   // sAgg/sAgp complete; uraw free for node aliases

    // ---------- NODE + pre(l+1) epilogue: single wave, 16 nodes ----------
    if (t < 64) {
        const int nbase = bx << 4;             // g*128 + qp*16
        float* __restrict__ HAout = ws + (op ? OFF_HA1 : OFF_HA0);
        unsigned short* __restrict__ HBout = (unsigned short*)(ws + (op ? OFF_HB1 : OFF_HB0));
        float* __restrict__ Pout = ws + (op ? OFF_P1 : OFF_P0);

        // stage h (16 rows x 32 f32)
        {
            const int row = lane >> 2, seg = lane & 3;
            const float* hsrc = ws + OFF_H + (nbase + row) * 32 + (seg << 3);
#pragma unroll
            for (int j = 0; j < 8; ++j) sH[row][(seg << 3) + j] = hsrc[j];
        }

        const float* __restrict__ Wn1 = W_node1 + l * 2048;
        const float* __restrict__ Wn2 = W_node2 + l * 1024;
        const float* __restrict__ W1  = W_msg1 + (l + 1) * 97 * 32;
        bf16x8 B1[2][2], B2[2], Ba[2], Bb[2];
#pragma unroll
        for (int j = 0; j < 8; ++j) {
            const int pk = ((kk + j) & 1) * 16 + ((kk + j) >> 1);
#pragma unroll
            for (int nh = 0; nh < 2; ++nh) {
                B1[0][nh][j] = f2bfs(Wn1[(kk + j) * 32 + nh * 16 + c]);
                B1[1][nh][j] = f2bfs(Wn1[(32 + kk + j) * 32 + nh * 16 + c]);
                B2[nh][j]    = f2bfs(Wn2[pk * 32 + nh * 16 + c]);
                Ba[nh][j]    = f2bfs(W1[pk * 32 + nh * 16 + c]);
                Bb[nh][j]    = f2bfs(W1[(32 + pk) * 32 + nh * 16 + c]);
            }
        }

        // temb chain (redundant per block; one writer block per graph)
        const int c2 = lane & 31;
        const float* __restrict__ tin = ws + (par ? OFF_TEMB1 : OFF_TEMB0) + g * 32;
        const float* __restrict__ Wt = W_t + l * 1024;
        float a2 = b_t[l * 32 + c2];
#pragma unroll
        for (int k = 0; k < 32; ++k) a2 += tin[k] * Wt[k * 32 + c2];
        const float tnew = fsilu(a2);
        float tv = b_msg1[(l + 1) * 32 + c2];
#pragma unroll
        for (int k = 0; k < 32; ++k) tv += __shfl(tnew, k) * W1[(65 + k) * 32 + c2];
        if ((bx & 7) == 0 && lane < 32)
            ws[(par ? OFF_TEMB0 : OFF_TEMB1) + g * 32 + lane] = tnew;

        // GEMM1: [h | aggh] @ Wn1
        union { unsigned int u[4]; bf16x8 v; } A0, A1;
#pragma unroll
        for (int d = 0; d < 4; ++d) {
            A0.u[d] = pk_trunc(sH[c][kk + 2 * d],   sH[c][kk + 2 * d + 1]);
            A1.u[d] = pk_trunc(sAgg[c][kk + 2 * d], sAgg[c][kk + 2 * d + 1]);
        }
        f32x4 u1[2];
#pragma unroll
        for (int nh = 0; nh < 2; ++nh) {
            const float bb = b_node1[l * 32 + nh * 16 + c];
            f32x4 acc = (f32x4){bb, bb, bb, bb};
            acc = __builtin_amdgcn_mfma_f32_16x16x32_bf16(A0.v, B1[0][nh], acc, 0, 0, 0);
            acc = __builtin_amdgcn_mfma_f32_16x16x32_bf16(A1.v, B1[1][nh], acc, 0, 0, 0);
            u1[nh] = acc;
        }

        // GEMM2
#pragma unroll
        for (int j = 0; j < 4; ++j)
            nmb[((rg << 2) + j) * 20 + c] = pk_trunc(fsilu(u1[0][j]), fsilu(u1[1][j]));
        union { uint4 q; bf16x8 v; } qa;
        qa.q = *(const uint4*)(nmb + c * 20 + (rg << 2));
        f32x4 u2[2];
#pragma unroll
        for (int nh = 0; nh < 2; ++nh) {
            const float bb = b_node2[l * 32 + nh * 16 + c];
            f32x4 acc = (f32x4){bb, bb, bb, bb};
            u2[nh] = __builtin_amdgcn_mfma_f32_16x16x32_bf16(qa.v, B2[nh], acc, 0, 0, 0);
        }

        // h' = leaky + residual; store + pi-stage
        float hp0[4], hp1[4];
#pragma unroll
        for (int j = 0; j < 4; ++j) {
            const int row = (rg << 2) + j;
            const float h0 = sH[row][c], h1 = sH[row][c + 16];
            const float v0 = u2[0][j], v1 = u2[1][j];
            hp0[j] = (v0 > 0.f ? v0 : 0.01f * v0) + h0;
            hp1[j] = (v1 > 0.f ? v1 : 0.01f * v1) + h1;
            ws[OFF_H + (nbase + row) * 32 + c]      = hp0[j];
            ws[OFF_H + (nbase + row) * 32 + c + 16] = hp1[j];
            nmb[row * 20 + c] = pk_trunc(hp0[j], hp1[j]);
        }

        // fused pre(l+1): HA/HB via MFMA -> opposite-parity buffers
        qa.q = *(const uint4*)(nmb + c * 20 + (rg << 2));
        f32x4 ha[2], hb[2];
        {
            f32x4 zz = (f32x4){0.f, 0.f, 0.f, 0.f};
#pragma unroll
            for (int nh = 0; nh < 2; ++nh) {
                ha[nh] = __builtin_amdgcn_mfma_f32_16x16x32_bf16(qa.v, Ba[nh], zz, 0, 0, 0);
                hb[nh] = __builtin_amdgcn_mfma_f32_16x16x32_bf16(qa.v, Bb[nh], zz, 0, 0, 0);
            }
        }
        const float tv0 = __shfl(tv, c), tv1 = __shfl(tv, c + 16);
#pragma unroll
        for (int j = 0; j < 4; ++j) {
            const int node = nbase + (rg << 2) + j;
            HAout[node * 32 + c]      = ha[0][j] + tv0;
            HAout[node * 32 + c + 16] = ha[1][j] + tv1;
            HBout[node * 32 + c]      = (unsigned short)f2bfs(hb[0][j]);
            HBout[node * 32 + c + 16] = (unsigned short)f2bfs(hb[1][j]);
        }

        // p' = p + aggp -> opposite-parity buffer
        if (lane < 32) {
            const int dl2 = lane >> 1, d = lane & 1;
            const int node = nbase + dl2;
            const float ag = d ? sAgp[dl2].y : sAgp[dl2].x;
            Pout[node * 2 + d] = (par ? ws[OFF_P1 + node * 2 + d]
                                      : ws[OFF_P0 + node * 2 + d]) + ag;
        }
    }
}

// ---------------- launch ----------------
extern "C" void kernel_launch(void* const* d_in, const int* in_sizes, int n_in,
                              void* d_out, int out_size, void* d_ws, size_t ws_size,
                              hipStream_t stream)
{
    const float* pos      = (const float*)d_in[0];
    const int*   tsteps   = (const int*)d_in[1];
    const float* goal_pos = (const float*)d_in[2];
    const float* W_hin    = (const float*)d_in[3];
    const float* b_hin    = (const float*)d_in[4];
    const float* W_msg1   = (const float*)d_in[5];
    const float* b_msg1   = (const float*)d_in[6];
    const float* W_msg2   = (const float*)d_in[7];
    const float* b_msg2   = (const float*)d_in[8];
    const float* W_att    = (const float*)d_in[9];
    const float* b_att    = (const float*)d_in[10];
    const float* W_pos1   = (const float*)d_in[11];
    const float* b_pos1   = (const float*)d_in[12];
    const float* W_pos2   = (const float*)d_in[13];
    const float* b_pos2   = (const float*)d_in[14];
    const float* W_node1  = (const float*)d_in[15];
    const float* b_node1  = (const float*)d_in[16];
    const float* W_node2  = (const float*)d_in[17];
    const float* b_node2  = (const float*)d_in[18];
    const float* W_t      = (const float*)d_in[19];
    const float* b_t      = (const float*)d_in[20];

    float* ws = (float*)d_ws;

    setup_pre_kernel<<<1024, 256, 0, stream>>>(ws, pos, tsteps, goal_pos,
                                               W_hin, b_hin, W_msg1, b_msg1);

    for (int l = 0; l < L; ++l)
        edge_kernel<<<512, 256, 0, stream>>>(ws, W_msg1, b_msg1, W_msg2, b_msg2,
                                             W_att, b_att, W_pos1, b_pos1,
                                             W_pos2, b_pos2, W_node1, b_node1,
                                             W_node2, b_node2, W_t, b_t,
                                             (float*)d_out, l);
}